// Round 5
// baseline (398.765 us; speedup 1.0000x reference)
//
#include <hip/hip_runtime.h>
#include <stdint.h>

#define B_  4
#define S_  2048
#define C_  1024
#define NH_ 16
#define HD_ 64
#define M_  (B_*S_)   // 8192
#define NT_ (S_/64)   // 32 q/k tiles

typedef __attribute__((ext_vector_type(8))) short bf16x8;
typedef __attribute__((ext_vector_type(4))) float f32x4;

typedef __attribute__((address_space(1))) const unsigned int gu32;
typedef __attribute__((address_space(3))) unsigned int lu32;

__device__ __forceinline__ void gload16(const void* g, void* l) {
    __builtin_amdgcn_global_load_lds((gu32*)g, (lu32*)l, 16, 0, 0);
}

__device__ __forceinline__ unsigned short f2bf(float f) {
    union { float f; unsigned u; } v; v.f = f;
    unsigned r = v.u + 0x7FFF + ((v.u >> 16) & 1);   // RNE
    return (unsigned short)(r >> 16);
}

// ---------------- fused f32 -> bf16 convert (5 segments, 1 launch) ----------------
__global__ __launch_bounds__(256)
void cvt_all(const float4* __restrict__ x, const float4* __restrict__ y,
             const float4* __restrict__ wq, const float4* __restrict__ wkv,
             const float4* __restrict__ wo,
             uint4* __restrict__ xb, uint4* __restrict__ yb, uint4* __restrict__ wqb,
             uint4* __restrict__ wkvb, uint4* __restrict__ wob) {
    int i = blockIdx.x * 256 + threadIdx.x;
    const float4* src; uint4* dst; int off;
    if      (i < 1048576) { src = x;   dst = xb;   off = i; }
    else if (i < 2097152) { src = y;   dst = yb;   off = i - 1048576; }
    else if (i < 2228224) { src = wq;  dst = wqb;  off = i - 2097152; }
    else if (i < 2490368) { src = wkv; dst = wkvb; off = i - 2228224; }
    else                  { src = wo;  dst = wob;  off = i - 2490368; }
    float4 a = src[2*off], b = src[2*off+1];
    union { unsigned short s[8]; uint4 v; } u;
    u.s[0]=f2bf(a.x); u.s[1]=f2bf(a.y); u.s[2]=f2bf(a.z); u.s[3]=f2bf(a.w);
    u.s[4]=f2bf(b.x); u.s[5]=f2bf(b.y); u.s[6]=f2bf(b.z); u.s[7]=f2bf(b.w);
    dst[off] = u.v;
}

// ---------------- mask bytes -> per-tile 64-bit masks ----------------
__global__ __launch_bounds__(64)
void mask_bits(const unsigned char* __restrict__ mp, unsigned long long* __restrict__ mw) {
    int b = blockIdx.x, lane = threadIdx.x;
    for (int w = 0; w < NT_; ++w) {
        unsigned long long bal = __ballot(mp[b*S_ + w*64 + lane] != 0);
        if (lane == 0) mw[b*NT_ + w] = bal;
    }
}

// ---------------- GEMM: C[m][n] = sum_k A[m][k]*Bt[n][k] + bias[n] ----------------
#define BM 128
#define BN 128
#define BK 64

template<int MODE>
__global__ __launch_bounds__(256)
void gemm_bt(const unsigned short* __restrict__ A, const unsigned short* __restrict__ Bt,
             const float* __restrict__ bias,
             unsigned short* __restrict__ out0, unsigned short* __restrict__ out1,
             float* __restrict__ outf, int K, int N)
{
    __shared__ unsigned short As[BM*BK];
    __shared__ unsigned short Bs[BN*BK];
    int t = threadIdx.x;
    int lane = t & 63, w = t >> 6;
    int wx = w & 1, wy = w >> 1;
    int quad = lane >> 4, l16 = lane & 15;
    int bx = blockIdx.x, by = blockIdx.y;

    f32x4 acc[4][4] = {};
    int rowA = by * BM, rowB = bx * BN;
    int lr = lane >> 3;
    int lc = (lane & 7) * 8;
    const unsigned short* gA = A  + (size_t)(rowA + w*32 + lr)*K + lc;
    const unsigned short* gB = Bt + (size_t)(rowB + w*32 + lr)*K + lc;
    unsigned short* lA = &As[(w*32)*BK];
    unsigned short* lB = &Bs[(w*32)*BK];

    for (int kb = 0; kb < K; kb += BK) {
        #pragma unroll
        for (int i = 0; i < 4; ++i) {
            gload16(gA + (size_t)i*8*K + kb, lA + i*8*BK);
            gload16(gB + (size_t)i*8*K + kb, lB + i*8*BK);
        }
        asm volatile("s_waitcnt vmcnt(0)" ::: "memory");
        __syncthreads();
        #pragma unroll
        for (int ks = 0; ks < 2; ++ks) {
            bf16x8 af[4], bfr[4];
            #pragma unroll
            for (int mt = 0; mt < 4; ++mt)
                af[mt] = *reinterpret_cast<const bf16x8*>(&As[(wy*64 + mt*16 + l16)*BK + ks*32 + quad*8]);
            #pragma unroll
            for (int nt = 0; nt < 4; ++nt)
                bfr[nt] = *reinterpret_cast<const bf16x8*>(&Bs[(wx*64 + nt*16 + l16)*BK + ks*32 + quad*8]);
            #pragma unroll
            for (int mt = 0; mt < 4; ++mt)
                #pragma unroll
                for (int nt = 0; nt < 4; ++nt)
                    acc[mt][nt] = __builtin_amdgcn_mfma_f32_16x16x32_bf16(af[mt], bfr[nt], acc[mt][nt], 0, 0, 0);
        }
        __syncthreads();
    }

    const float QSCALE = 0.180336880111f;  // 0.125 * log2(e)
    #pragma unroll
    for (int mt = 0; mt < 4; ++mt) {
        #pragma unroll
        for (int nt = 0; nt < 4; ++nt) {
            int gn = bx*BN + wx*64 + nt*16 + l16;
            float bv = bias[gn];
            #pragma unroll
            for (int r = 0; r < 4; ++r) {
                int gm = by*BM + wy*64 + mt*16 + quad*4 + r;
                float v = acc[mt][nt][r] + bv;
                if (MODE == 2) {
                    outf[(size_t)gm * N + gn] = v;
                } else if (MODE == 0) {
                    v *= QSCALE;
                    int b = gm >> 11, s = gm & 2047;
                    int h = gn >> 6,  d = gn & 63;
                    out0[(((size_t)(b*NH_ + h)*S_ + s) << 6) + d] = f2bf(v);
                } else {
                    int b = gm >> 11, s = gm & 2047;
                    if (gn < C_) {
                        int h = gn >> 6, d = gn & 63;
                        out0[(((size_t)(b*NH_ + h)*S_ + s) << 6) + d] = f2bf(v);
                    } else {
                        int n2 = gn - C_;
                        int h = n2 >> 6, d = n2 & 63;
                        out1[((size_t)(b*NH_ + h)*HD_ + d)*S_ + s] = f2bf(v);
                    }
                }
            }
        }
    }
}

// ---------------- Flash attention, v4 ----------------
// Wave w owns k-slice [w*16,+16). S^T via mfma(kf,qf): lane holds
// P^T[k=w*16+quad*4+r][q=m*16+l16] — which IS the A-operand layout (row=l16=q,
// k=quad*4+r) of a K=16 PV product. PV partial (wave's 16 k, full 64 d) is done
// with 16x16x32 MFMA, zero-padding the upper K half of A (packed P) and B (V,
// one dwordx2: 4 consecutive s = k). NO LDS / NO barriers in the K loop.
// O partials reduced across 4 waves once per q-tile via 2-phase LDS (66-f stride
// = 2-way conflict-free). Balanced causal grid: block does qt=qi and 31-qi.
__global__ __launch_bounds__(256, 3)
void attn_kernel(const unsigned short* __restrict__ Qg, const unsigned short* __restrict__ Kg,
                 const unsigned short* __restrict__ Vt, const unsigned long long* __restrict__ mw,
                 unsigned short* __restrict__ att)
{
    __shared__ float Obuf[2][64*66];
    __shared__ float Lbuf[4][64];
    __shared__ float Linv[64];
    int t = threadIdx.x, lane = t & 63, w = t >> 6;
    int quad = lane >> 4, l16 = lane & 15;
    int bh = blockIdx.x, b = bh >> 4, h = bh & 15;
    int qi = blockIdx.y;

    const unsigned short* kbase = Kg + ((size_t)bh*S_ + w*16 + l16)*HD_ + quad*8;
    // V B-frag: row d = l16 (+nt*16), col s = kt*64 + w*16 + quad*4 (4 consecutive)
    const unsigned short* vbase = Vt + ((size_t)bh*HD_ + l16)*S_ + w*16 + quad*4;

    for (int half = 0; half < 2; ++half) {
        int qt = half ? (NT_ - 1 - qi) : qi;

        bf16x8 qf[4][2];
        #pragma unroll
        for (int m = 0; m < 4; ++m) {
            const unsigned short* qp = Qg + ((size_t)bh*S_ + qt*64 + m*16 + l16)*HD_;
            qf[m][0] = *reinterpret_cast<const bf16x8*>(qp + quad*8);
            qf[m][1] = *reinterpret_cast<const bf16x8*>(qp + 32 + quad*8);
        }
        f32x4 oacc[4][4] = {};
        float lsum[4] = {0.f, 0.f, 0.f, 0.f};

        bf16x8 kc0 = *reinterpret_cast<const bf16x8*>(kbase);
        bf16x8 kc1 = *reinterpret_cast<const bf16x8*>(kbase + 32);

        for (int kt = 0; kt <= qt; ++kt) {
            int ktn = (kt < qt) ? kt + 1 : kt;
            const unsigned short* kpn = kbase + (size_t)ktn*64*HD_;
            bf16x8 kn0 = *reinterpret_cast<const bf16x8*>(kpn);
            bf16x8 kn1 = *reinterpret_cast<const bf16x8*>(kpn + 32);

            // V B-frags (upper K half zero)
            bf16x8 vB[4];
            const unsigned short* vp = vbase + kt*64;
            #pragma unroll
            for (int nt = 0; nt < 4; ++nt) {
                uint2 raw = *reinterpret_cast<const uint2*>(vp + (size_t)nt*16*S_);
                union { unsigned u[4]; bf16x8 v; } vb;
                vb.u[0] = raw.x; vb.u[1] = raw.y; vb.u[2] = 0; vb.u[3] = 0;
                vB[nt] = vb.v;
            }

            // S^T: lane holds S^T[k = w*16+quad*4+r][q = m*16+l16]
            f32x4 sacc[4];
            #pragma unroll
            for (int m = 0; m < 4; ++m) {
                sacc[m] = __builtin_amdgcn_mfma_f32_16x16x32_bf16(kc0, qf[m][0], f32x4{}, 0, 0, 0);
                sacc[m] = __builtin_amdgcn_mfma_f32_16x16x32_bf16(kc1, qf[m][1], sacc[m], 0, 0, 0);
            }

            unsigned long long mword = mw[b*NT_ + kt];
            unsigned nib = (unsigned)(mword >> (w*16 + quad*4)) & 0xFu;
            float padd[4];
            #pragma unroll
            for (int r = 0; r < 4; ++r) padd[r] = ((nib >> r) & 1u) ? -1e30f : 0.f;
            bool diag = (kt == qt);

            #pragma unroll
            for (int m = 0; m < 4; ++m) {
                if (diag && w > m) continue;   // block fully above diagonal: P==0
                float p[4];
                #pragma unroll
                for (int r = 0; r < 4; ++r) {
                    float s = sacc[m][r] + padd[r];
                    if (diag && w == m && (quad*4 + r > l16)) s = -1e30f;
                    p[r] = __builtin_amdgcn_exp2f(s);
                }
                lsum[m] += (p[0] + p[1]) + (p[2] + p[3]);
                unsigned pk01 = __builtin_amdgcn_perm(__float_as_uint(p[1]), __float_as_uint(p[0]), 0x07060302u);
                unsigned pk23 = __builtin_amdgcn_perm(__float_as_uint(p[3]), __float_as_uint(p[2]), 0x07060302u);
                union { unsigned u[4]; bf16x8 v; } pa;
                pa.u[0] = pk01; pa.u[1] = pk23; pa.u[2] = 0; pa.u[3] = 0;
                #pragma unroll
                for (int nt = 0; nt < 4; ++nt)
                    oacc[m][nt] = __builtin_amdgcn_mfma_f32_16x16x32_bf16(pa.v, vB[nt], oacc[m][nt], 0, 0, 0);
            }
            kc0 = kn0; kc1 = kn1;
        }

        // ---- epilogue: cross-wave O + l reduction ----
        #pragma unroll
        for (int m = 0; m < 4; ++m) {
            lsum[m] += __shfl_xor(lsum[m], 16, 64);
            lsum[m] += __shfl_xor(lsum[m], 32, 64);
            Lbuf[w][m*16 + l16] = lsum[m];
        }
        if (w < 2) {
            #pragma unroll
            for (int m = 0; m < 4; ++m)
                #pragma unroll
                for (int nt = 0; nt < 4; ++nt)
                    #pragma unroll
                    for (int r = 0; r < 4; ++r)
                        Obuf[w][(m*16 + quad*4 + r)*66 + nt*16 + l16] = oacc[m][nt][r];
        }
        __syncthreads();
        if (w >= 2) {
            float* ob = Obuf[w - 2];
            #pragma unroll
            for (int m = 0; m < 4; ++m)
                #pragma unroll
                for (int nt = 0; nt < 4; ++nt)
                    #pragma unroll
                    for (int r = 0; r < 4; ++r)
                        ob[(m*16 + quad*4 + r)*66 + nt*16 + l16] += oacc[m][nt][r];
        }
        int q64 = t & 63;
        Linv[q64] = 1.0f / (Lbuf[0][q64] + Lbuf[1][q64] + Lbuf[2][q64] + Lbuf[3][q64]);
        __syncthreads();
        #pragma unroll
        for (int nt = 0; nt < 4; ++nt) {
            #pragma unroll
            for (int r = 0; r < 4; ++r) {
                int row = w*16 + quad*4 + r;
                float v = Obuf[0][row*66 + nt*16 + l16] + Obuf[1][row*66 + nt*16 + l16];
                att[((size_t)(b*S_ + qt*64 + row))*C_ + h*HD_ + nt*16 + l16] = f2bf(v * Linv[row]);
            }
        }
        __syncthreads();   // Obuf/Linv reuse barrier before next half
    }
}

// ---------------- launch ----------------
extern "C" void kernel_launch(void* const* d_in, const int* in_sizes, int n_in,
                              void* d_out, int out_size, void* d_ws, size_t ws_size,
                              hipStream_t stream) {
    const float* x     = (const float*)d_in[0];
    const float* y     = (const float*)d_in[1];
    const unsigned char* mask = (const unsigned char*)d_in[2];
    const float* Wq_w  = (const float*)d_in[3];
    const float* Wq_b  = (const float*)d_in[4];
    const float* Wkv_w = (const float*)d_in[5];
    const float* Wkv_b = (const float*)d_in[6];
    const float* Wo_w  = (const float*)d_in[7];
    const float* Wo_b  = (const float*)d_in[8];
    float* out = (float*)d_out;

    unsigned short* xb   = (unsigned short*)d_ws;
    unsigned short* yb   = xb   + (size_t)M_*C_;
    unsigned short* Wqb  = yb   + (size_t)M_*C_;
    unsigned short* Wkvb = Wqb  + (size_t)C_*C_;
    unsigned short* Wob  = Wkvb + (size_t)2*C_*C_;
    unsigned short* Qg   = Wob  + (size_t)C_*C_;
    unsigned short* Kg   = Qg   + (size_t)M_*C_;
    unsigned short* Vtg  = Kg   + (size_t)M_*C_;
    unsigned long long* maskw = (unsigned long long*)yb;  // yb dead after KV proj
    unsigned short* att  = xb;                            // xb dead after Q proj

    cvt_all<<<10240, 256, 0, stream>>>((const float4*)x, (const float4*)y,
        (const float4*)Wq_w, (const float4*)Wkv_w, (const float4*)Wo_w,
        (uint4*)xb, (uint4*)yb, (uint4*)Wqb, (uint4*)Wkvb, (uint4*)Wob);

    gemm_bt<0><<<dim3(C_/BN, M_/BM), 256, 0, stream>>>(xb, Wqb, Wq_b, Qg, nullptr, nullptr, C_, C_);
    gemm_bt<1><<<dim3(2*C_/BN, M_/BM), 256, 0, stream>>>(yb, Wkvb, Wkv_b, Kg, Vtg, nullptr, C_, 2*C_);
    mask_bits<<<B_, 64, 0, stream>>>(mask, maskw);   // after KV proj: yb dead now
    attn_kernel<<<dim3(B_*NH_, NT_/2), 256, 0, stream>>>(Qg, Kg, Vtg, maskw, att);
    gemm_bt<2><<<dim3(C_/BN, M_/BM), 256, 0, stream>>>(att, Wob, Wo_b, nullptr, nullptr, out, C_, C_);
}

// Round 6
// 362.135 us; speedup vs baseline: 1.1012x; 1.1012x over previous
//
#include <hip/hip_runtime.h>
#include <stdint.h>

#define B_  4
#define S_  2048
#define C_  1024
#define NH_ 16
#define HD_ 64
#define M_  (B_*S_)   // 8192
#define NT_ (S_/64)   // 32 q/k tiles

typedef __attribute__((ext_vector_type(8))) short bf16x8;
typedef __attribute__((ext_vector_type(4))) float f32x4;

typedef __attribute__((address_space(1))) const unsigned int gu32;
typedef __attribute__((address_space(3))) unsigned int lu32;

__device__ __forceinline__ void gload16(const void* g, void* l) {
    __builtin_amdgcn_global_load_lds((gu32*)g, (lu32*)l, 16, 0, 0);
}

__device__ __forceinline__ unsigned short f2bf(float f) {
    union { float f; unsigned u; } v; v.f = f;
    unsigned r = v.u + 0x7FFF + ((v.u >> 16) & 1);   // RNE
    return (unsigned short)(r >> 16);
}

// ---------------- fused f32 -> bf16 convert (5 segments, 1 launch) ----------------
__global__ __launch_bounds__(256)
void cvt_all(const float4* __restrict__ x, const float4* __restrict__ y,
             const float4* __restrict__ wq, const float4* __restrict__ wkv,
             const float4* __restrict__ wo,
             uint4* __restrict__ xb, uint4* __restrict__ yb, uint4* __restrict__ wqb,
             uint4* __restrict__ wkvb, uint4* __restrict__ wob) {
    int i = blockIdx.x * 256 + threadIdx.x;
    const float4* src; uint4* dst; int off;
    if      (i < 1048576) { src = x;   dst = xb;   off = i; }
    else if (i < 2097152) { src = y;   dst = yb;   off = i - 1048576; }
    else if (i < 2228224) { src = wq;  dst = wqb;  off = i - 2097152; }
    else if (i < 2490368) { src = wkv; dst = wkvb; off = i - 2228224; }
    else                  { src = wo;  dst = wob;  off = i - 2490368; }
    float4 a = src[2*off], b = src[2*off+1];
    union { unsigned short s[8]; uint4 v; } u;
    u.s[0]=f2bf(a.x); u.s[1]=f2bf(a.y); u.s[2]=f2bf(a.z); u.s[3]=f2bf(a.w);
    u.s[4]=f2bf(b.x); u.s[5]=f2bf(b.y); u.s[6]=f2bf(b.z); u.s[7]=f2bf(b.w);
    dst[off] = u.v;
}

// ---------------- mask bytes -> per-tile 64-bit masks ----------------
__global__ __launch_bounds__(64)
void mask_bits(const unsigned char* __restrict__ mp, unsigned long long* __restrict__ mw) {
    int b = blockIdx.x, lane = threadIdx.x;
    for (int w = 0; w < NT_; ++w) {
        unsigned long long bal = __ballot(mp[b*S_ + w*64 + lane] != 0);
        if (lane == 0) mw[b*NT_ + w] = bal;
    }
}

// ---------------- GEMM: C[m][n] = sum_k A[m][k]*Bt[n][k] + bias[n] ----------------
#define BM 128
#define BN 128
#define BK 64

template<int MODE>
__global__ __launch_bounds__(256)
void gemm_bt(const unsigned short* __restrict__ A, const unsigned short* __restrict__ Bt,
             const float* __restrict__ bias,
             unsigned short* __restrict__ out0, unsigned short* __restrict__ out1,
             float* __restrict__ outf, int K, int N)
{
    __shared__ unsigned short As[BM*BK];
    __shared__ unsigned short Bs[BN*BK];
    int t = threadIdx.x;
    int lane = t & 63, w = t >> 6;
    int wx = w & 1, wy = w >> 1;
    int quad = lane >> 4, l16 = lane & 15;
    int bx = blockIdx.x, by = blockIdx.y;

    f32x4 acc[4][4] = {};
    int rowA = by * BM, rowB = bx * BN;
    int lr = lane >> 3;
    int lc = (lane & 7) * 8;
    const unsigned short* gA = A  + (size_t)(rowA + w*32 + lr)*K + lc;
    const unsigned short* gB = Bt + (size_t)(rowB + w*32 + lr)*K + lc;
    unsigned short* lA = &As[(w*32)*BK];
    unsigned short* lB = &Bs[(w*32)*BK];

    for (int kb = 0; kb < K; kb += BK) {
        #pragma unroll
        for (int i = 0; i < 4; ++i) {
            gload16(gA + (size_t)i*8*K + kb, lA + i*8*BK);
            gload16(gB + (size_t)i*8*K + kb, lB + i*8*BK);
        }
        asm volatile("s_waitcnt vmcnt(0)" ::: "memory");
        __syncthreads();
        #pragma unroll
        for (int ks = 0; ks < 2; ++ks) {
            bf16x8 af[4], bfr[4];
            #pragma unroll
            for (int mt = 0; mt < 4; ++mt)
                af[mt] = *reinterpret_cast<const bf16x8*>(&As[(wy*64 + mt*16 + l16)*BK + ks*32 + quad*8]);
            #pragma unroll
            for (int nt = 0; nt < 4; ++nt)
                bfr[nt] = *reinterpret_cast<const bf16x8*>(&Bs[(wx*64 + nt*16 + l16)*BK + ks*32 + quad*8]);
            #pragma unroll
            for (int mt = 0; mt < 4; ++mt)
                #pragma unroll
                for (int nt = 0; nt < 4; ++nt)
                    acc[mt][nt] = __builtin_amdgcn_mfma_f32_16x16x32_bf16(af[mt], bfr[nt], acc[mt][nt], 0, 0, 0);
        }
        __syncthreads();
    }

    const float QSCALE = 0.180336880111f;  // 0.125 * log2(e)
    #pragma unroll
    for (int mt = 0; mt < 4; ++mt) {
        #pragma unroll
        for (int nt = 0; nt < 4; ++nt) {
            int gn = bx*BN + wx*64 + nt*16 + l16;
            float bv = bias[gn];
            #pragma unroll
            for (int r = 0; r < 4; ++r) {
                int gm = by*BM + wy*64 + mt*16 + quad*4 + r;
                float v = acc[mt][nt][r] + bv;
                if (MODE == 2) {
                    outf[(size_t)gm * N + gn] = v;
                } else if (MODE == 0) {
                    v *= QSCALE;
                    int b = gm >> 11, s = gm & 2047;
                    int h = gn >> 6,  d = gn & 63;
                    out0[(((size_t)(b*NH_ + h)*S_ + s) << 6) + d] = f2bf(v);
                } else {
                    int b = gm >> 11, s = gm & 2047;
                    if (gn < C_) {
                        int h = gn >> 6, d = gn & 63;
                        out0[(((size_t)(b*NH_ + h)*S_ + s) << 6) + d] = f2bf(v);
                    } else {
                        int n2 = gn - C_;
                        int h = n2 >> 6, d = n2 & 63;
                        out1[((size_t)(b*NH_ + h)*HD_ + d)*S_ + s] = f2bf(v);
                    }
                }
            }
        }
    }
}

// ---------------- Flash attention, v5 (v3.1 structure, 2 k-tiles per barrier) ----
// Wave w owns k-slice / d-slice [w*16,+16). Per pair (ktA,ktB): S^T via mfma(kf,qf)
// for both tiles, P packed to one 64x(128+8) LDS tile, ONE barrier pair, then
// 4 full-K=32 PV MFMAs per m-block. Diagonal: chunk-B of last pair (qt odd) or a
// single-tile tail (qt even) identical to v3.1's body. Epilogue as v3.1 (quad-
// reduced lsum, cross-wave Lbuf, store O/l).
#define PLD 136   // P row stride in shorts (128 + 8): 68 dw -> 2-way conflicts only
__global__ __launch_bounds__(256, 3)
void attn_kernel(const unsigned short* __restrict__ Qg, const unsigned short* __restrict__ Kg,
                 const unsigned short* __restrict__ Vt, const unsigned long long* __restrict__ mw,
                 unsigned short* __restrict__ att)
{
    __shared__ unsigned short Pl[64*PLD];
    __shared__ float Lbuf[4][64];
    __shared__ float Linv[64];
    int t = threadIdx.x, lane = t & 63, w = t >> 6;
    int quad = lane >> 4, l16 = lane & 15;
    int bh = blockIdx.x, b = bh >> 4, h = bh & 15;
    int qi = blockIdx.y;

    const unsigned short* kbase = Kg + ((size_t)bh*S_ + w*16 + l16)*HD_ + quad*8;
    const unsigned short* vbase = Vt + ((size_t)bh*HD_ + w*16 + l16)*S_ + quad*8;
    int kp_row = w*16 + quad*4;   // lane's k-row base within a tile

    for (int half = 0; half < 2; ++half) {
        int qt = half ? (NT_ - 1 - qi) : qi;

        bf16x8 qf[4][2];
        #pragma unroll
        for (int m = 0; m < 4; ++m) {
            const unsigned short* qp = Qg + ((size_t)bh*S_ + qt*64 + m*16 + l16)*HD_;
            qf[m][0] = *reinterpret_cast<const bf16x8*>(qp + quad*8);
            qf[m][1] = *reinterpret_cast<const bf16x8*>(qp + 32 + quad*8);
        }
        f32x4 oacc[4] = {};
        float lsum[4] = {0.f, 0.f, 0.f, 0.f};

        int npairs = (qt + 1) >> 1;
        bool tail = ((qt + 1) & 1) != 0;

        for (int p2 = 0; p2 < npairs; ++p2) {
            int ktA = 2*p2, ktB = 2*p2 + 1;
            bool diagB = (!tail && p2 == npairs - 1);

            const unsigned short* kpA = kbase + (size_t)ktA*64*HD_;
            const unsigned short* kpB = kbase + (size_t)ktB*64*HD_;
            bf16x8 kA0 = *reinterpret_cast<const bf16x8*>(kpA);
            bf16x8 kA1 = *reinterpret_cast<const bf16x8*>(kpA + 32);
            bf16x8 kB0 = *reinterpret_cast<const bf16x8*>(kpB);
            bf16x8 kB1 = *reinterpret_cast<const bf16x8*>(kpB + 32);
            const unsigned short* vpA = vbase + ktA*64;
            const unsigned short* vpB = vbase + ktB*64;
            bf16x8 vA0 = *reinterpret_cast<const bf16x8*>(vpA);
            bf16x8 vA1 = *reinterpret_cast<const bf16x8*>(vpA + 32);
            bf16x8 vB0 = *reinterpret_cast<const bf16x8*>(vpB);
            bf16x8 vB1 = *reinterpret_cast<const bf16x8*>(vpB + 32);

            unsigned nibA = (unsigned)(mw[b*NT_ + ktA] >> (w*16 + quad*4)) & 0xFu;
            unsigned nibB = (unsigned)(mw[b*NT_ + ktB] >> (w*16 + quad*4)) & 0xFu;
            float paddA[4], paddB[4];
            #pragma unroll
            for (int r = 0; r < 4; ++r) {
                paddA[r] = ((nibA >> r) & 1u) ? -1e30f : 0.f;
                paddB[r] = ((nibB >> r) & 1u) ? -1e30f : 0.f;
            }

            #pragma unroll
            for (int m = 0; m < 4; ++m) {
                // chunk A (never diagonal: ktA <= qt-1)
                f32x4 sa = __builtin_amdgcn_mfma_f32_16x16x32_bf16(kA0, qf[m][0], f32x4{}, 0, 0, 0);
                sa = __builtin_amdgcn_mfma_f32_16x16x32_bf16(kA1, qf[m][1], sa, 0, 0, 0);
                float pA[4];
                #pragma unroll
                for (int r = 0; r < 4; ++r) pA[r] = __builtin_amdgcn_exp2f(sa[r] + paddA[r]);
                lsum[m] += (pA[0] + pA[1]) + (pA[2] + pA[3]);
                unsigned a01 = __builtin_amdgcn_perm(__float_as_uint(pA[1]), __float_as_uint(pA[0]), 0x07060302u);
                unsigned a23 = __builtin_amdgcn_perm(__float_as_uint(pA[3]), __float_as_uint(pA[2]), 0x07060302u);
                *reinterpret_cast<uint2*>(&Pl[(m*16 + l16)*PLD + w*16 + quad*4]) = make_uint2(a01, a23);
                // chunk B (diagonal iff diagB)
                f32x4 sb = __builtin_amdgcn_mfma_f32_16x16x32_bf16(kB0, qf[m][0], f32x4{}, 0, 0, 0);
                sb = __builtin_amdgcn_mfma_f32_16x16x32_bf16(kB1, qf[m][1], sb, 0, 0, 0);
                float pB[4];
                #pragma unroll
                for (int r = 0; r < 4; ++r) {
                    float s = sb[r] + paddB[r];
                    if (diagB && (kp_row + r > m*16 + l16)) s = -1e30f;
                    pB[r] = __builtin_amdgcn_exp2f(s);
                }
                lsum[m] += (pB[0] + pB[1]) + (pB[2] + pB[3]);
                unsigned b01 = __builtin_amdgcn_perm(__float_as_uint(pB[1]), __float_as_uint(pB[0]), 0x07060302u);
                unsigned b23 = __builtin_amdgcn_perm(__float_as_uint(pB[3]), __float_as_uint(pB[2]), 0x07060302u);
                *reinterpret_cast<uint2*>(&Pl[(m*16 + l16)*PLD + 64 + w*16 + quad*4]) = make_uint2(b01, b23);
            }
            __syncthreads();
            #pragma unroll
            for (int m = 0; m < 4; ++m) {
                const unsigned short* prow = &Pl[(m*16 + l16)*PLD + quad*8];
                bf16x8 pf0 = *reinterpret_cast<const bf16x8*>(prow);
                bf16x8 pf1 = *reinterpret_cast<const bf16x8*>(prow + 32);
                bf16x8 pf2 = *reinterpret_cast<const bf16x8*>(prow + 64);
                bf16x8 pf3 = *reinterpret_cast<const bf16x8*>(prow + 96);
                oacc[m] = __builtin_amdgcn_mfma_f32_16x16x32_bf16(pf0, vA0, oacc[m], 0, 0, 0);
                oacc[m] = __builtin_amdgcn_mfma_f32_16x16x32_bf16(pf1, vA1, oacc[m], 0, 0, 0);
                oacc[m] = __builtin_amdgcn_mfma_f32_16x16x32_bf16(pf2, vB0, oacc[m], 0, 0, 0);
                oacc[m] = __builtin_amdgcn_mfma_f32_16x16x32_bf16(pf3, vB1, oacc[m], 0, 0, 0);
            }
            __syncthreads();
        }

        if (tail) {   // single diagonal tile kt = qt (v3.1 body)
            int kt = qt;
            const unsigned short* kp = kbase + (size_t)kt*64*HD_;
            bf16x8 kc0 = *reinterpret_cast<const bf16x8*>(kp);
            bf16x8 kc1 = *reinterpret_cast<const bf16x8*>(kp + 32);
            const unsigned short* vp = vbase + kt*64;
            bf16x8 vc0 = *reinterpret_cast<const bf16x8*>(vp);
            bf16x8 vc1 = *reinterpret_cast<const bf16x8*>(vp + 32);
            unsigned nib = (unsigned)(mw[b*NT_ + kt] >> (w*16 + quad*4)) & 0xFu;
            float padd[4];
            #pragma unroll
            for (int r = 0; r < 4; ++r) padd[r] = ((nib >> r) & 1u) ? -1e30f : 0.f;

            #pragma unroll
            for (int m = 0; m < 4; ++m) {
                f32x4 sa = __builtin_amdgcn_mfma_f32_16x16x32_bf16(kc0, qf[m][0], f32x4{}, 0, 0, 0);
                sa = __builtin_amdgcn_mfma_f32_16x16x32_bf16(kc1, qf[m][1], sa, 0, 0, 0);
                float p[4];
                #pragma unroll
                for (int r = 0; r < 4; ++r) {
                    float s = sa[r] + padd[r];
                    if (kp_row + r > m*16 + l16) s = -1e30f;
                    p[r] = __builtin_amdgcn_exp2f(s);
                }
                lsum[m] += (p[0] + p[1]) + (p[2] + p[3]);
                unsigned a01 = __builtin_amdgcn_perm(__float_as_uint(p[1]), __float_as_uint(p[0]), 0x07060302u);
                unsigned a23 = __builtin_amdgcn_perm(__float_as_uint(p[3]), __float_as_uint(p[2]), 0x07060302u);
                *reinterpret_cast<uint2*>(&Pl[(m*16 + l16)*PLD + w*16 + quad*4]) = make_uint2(a01, a23);
            }
            __syncthreads();
            #pragma unroll
            for (int m = 0; m < 4; ++m) {
                const unsigned short* prow = &Pl[(m*16 + l16)*PLD + quad*8];
                bf16x8 pf0 = *reinterpret_cast<const bf16x8*>(prow);
                bf16x8 pf1 = *reinterpret_cast<const bf16x8*>(prow + 32);
                oacc[m] = __builtin_amdgcn_mfma_f32_16x16x32_bf16(pf0, vc0, oacc[m], 0, 0, 0);
                oacc[m] = __builtin_amdgcn_mfma_f32_16x16x32_bf16(pf1, vc1, oacc[m], 0, 0, 0);
            }
            __syncthreads();
        }

        // ---- epilogue: quad-reduce lsum, cross-wave L, store O/l ----
        #pragma unroll
        for (int m = 0; m < 4; ++m) {
            lsum[m] += __shfl_xor(lsum[m], 16, 64);
            lsum[m] += __shfl_xor(lsum[m], 32, 64);
            Lbuf[w][m*16 + l16] = lsum[m];
        }
        __syncthreads();
        int q64 = t & 63;
        Linv[q64] = 1.0f / (Lbuf[0][q64] + Lbuf[1][q64] + Lbuf[2][q64] + Lbuf[3][q64]);
        __syncthreads();
        #pragma unroll
        for (int m = 0; m < 4; ++m) {
            #pragma unroll
            for (int r = 0; r < 4; ++r) {
                float iv = Linv[m*16 + quad*4 + r];
                int q = qt*64 + m*16 + quad*4 + r;
                att[((size_t)(b*S_ + q))*C_ + h*HD_ + w*16 + l16] = f2bf(oacc[m][r] * iv);
            }
        }
        __syncthreads();   // Pl/Linv reuse barrier before next half
    }
}

// ---------------- launch ----------------
extern "C" void kernel_launch(void* const* d_in, const int* in_sizes, int n_in,
                              void* d_out, int out_size, void* d_ws, size_t ws_size,
                              hipStream_t stream) {
    const float* x     = (const float*)d_in[0];
    const float* y     = (const float*)d_in[1];
    const unsigned char* mask = (const unsigned char*)d_in[2];
    const float* Wq_w  = (const float*)d_in[3];
    const float* Wq_b  = (const float*)d_in[4];
    const float* Wkv_w = (const float*)d_in[5];
    const float* Wkv_b = (const float*)d_in[6];
    const float* Wo_w  = (const float*)d_in[7];
    const float* Wo_b  = (const float*)d_in[8];
    float* out = (float*)d_out;

    unsigned short* xb   = (unsigned short*)d_ws;
    unsigned short* yb   = xb   + (size_t)M_*C_;
    unsigned short* Wqb  = yb   + (size_t)M_*C_;
    unsigned short* Wkvb = Wqb  + (size_t)C_*C_;
    unsigned short* Wob  = Wkvb + (size_t)2*C_*C_;
    unsigned short* Qg   = Wob  + (size_t)C_*C_;
    unsigned short* Kg   = Qg   + (size_t)M_*C_;
    unsigned short* Vtg  = Kg   + (size_t)M_*C_;
    unsigned long long* maskw = (unsigned long long*)yb;  // yb dead after KV proj
    unsigned short* att  = xb;                            // xb dead after Q proj

    cvt_all<<<10240, 256, 0, stream>>>((const float4*)x, (const float4*)y,
        (const float4*)Wq_w, (const float4*)Wkv_w, (const float4*)Wo_w,
        (uint4*)xb, (uint4*)yb, (uint4*)Wqb, (uint4*)Wkvb, (uint4*)Wob);

    gemm_bt<0><<<dim3(C_/BN, M_/BM), 256, 0, stream>>>(xb, Wqb, Wq_b, Qg, nullptr, nullptr, C_, C_);
    gemm_bt<1><<<dim3(2*C_/BN, M_/BM), 256, 0, stream>>>(yb, Wkvb, Wkv_b, Kg, Vtg, nullptr, C_, 2*C_);
    mask_bits<<<B_, 64, 0, stream>>>(mask, maskw);   // after KV proj: yb dead now
    attn_kernel<<<dim3(B_*NH_, NT_/2), 256, 0, stream>>>(Qg, Kg, Vtg, maskw, att);
    gemm_bt<2><<<dim3(C_/BN, M_/BM), 256, 0, stream>>>(att, Wob, Wo_b, nullptr, nullptr, out, C_, C_);
}

// Round 7
// 328.687 us; speedup vs baseline: 1.2132x; 1.1018x over previous
//
#include <hip/hip_runtime.h>
#include <stdint.h>

#define B_  4
#define S_  2048
#define C_  1024
#define NH_ 16
#define HD_ 64
#define M_  (B_*S_)   // 8192
#define NT_ (S_/64)   // 32 q/k tiles

typedef __attribute__((ext_vector_type(8))) short bf16x8;
typedef __attribute__((ext_vector_type(4))) float f32x4;

typedef __attribute__((address_space(1))) const unsigned int gu32;
typedef __attribute__((address_space(3))) unsigned int lu32;

__device__ __forceinline__ void gload16(const void* g, void* l) {
    __builtin_amdgcn_global_load_lds((gu32*)g, (lu32*)l, 16, 0, 0);
}

__device__ __forceinline__ unsigned short f2bf(float f) {
    union { float f; unsigned u; } v; v.f = f;
    unsigned r = v.u + 0x7FFF + ((v.u >> 16) & 1);   // RNE
    return (unsigned short)(r >> 16);
}

// ---------------- fused f32 -> bf16 convert (5 segments, 1 launch) ----------------
__global__ __launch_bounds__(256)
void cvt_all(const float4* __restrict__ x, const float4* __restrict__ y,
             const float4* __restrict__ wq, const float4* __restrict__ wkv,
             const float4* __restrict__ wo,
             uint4* __restrict__ xb, uint4* __restrict__ yb, uint4* __restrict__ wqb,
             uint4* __restrict__ wkvb, uint4* __restrict__ wob) {
    int i = blockIdx.x * 256 + threadIdx.x;
    const float4* src; uint4* dst; int off;
    if      (i < 1048576) { src = x;   dst = xb;   off = i; }
    else if (i < 2097152) { src = y;   dst = yb;   off = i - 1048576; }
    else if (i < 2228224) { src = wq;  dst = wqb;  off = i - 2097152; }
    else if (i < 2490368) { src = wkv; dst = wkvb; off = i - 2228224; }
    else                  { src = wo;  dst = wob;  off = i - 2490368; }
    float4 a = src[2*off], b = src[2*off+1];
    union { unsigned short s[8]; uint4 v; } u;
    u.s[0]=f2bf(a.x); u.s[1]=f2bf(a.y); u.s[2]=f2bf(a.z); u.s[3]=f2bf(a.w);
    u.s[4]=f2bf(b.x); u.s[5]=f2bf(b.y); u.s[6]=f2bf(b.z); u.s[7]=f2bf(b.w);
    dst[off] = u.v;
}

// ---------------- GEMM body: C[m][n] = sum_k A[m][k]*Bt[n][k] + bias[n] -----------
#define BM 128
#define BN 128
#define BK 64

template<int MODE>
__device__ __forceinline__
void gemm_body(const unsigned short* __restrict__ A, const unsigned short* __restrict__ Bt,
               const float* __restrict__ bias,
               unsigned short* __restrict__ out0, unsigned short* __restrict__ out1,
               float* __restrict__ outf, int K, int N, int bx, int by,
               unsigned short* As, unsigned short* Bs)
{
    int t = threadIdx.x;
    int lane = t & 63, w = t >> 6;
    int wx = w & 1, wy = w >> 1;
    int quad = lane >> 4, l16 = lane & 15;

    f32x4 acc[4][4] = {};
    int rowA = by * BM, rowB = bx * BN;
    int lr = lane >> 3;
    int lc = (lane & 7) * 8;
    const unsigned short* gA = A  + (size_t)(rowA + w*32 + lr)*K + lc;
    const unsigned short* gB = Bt + (size_t)(rowB + w*32 + lr)*K + lc;
    unsigned short* lA = &As[(w*32)*BK];
    unsigned short* lB = &Bs[(w*32)*BK];

    for (int kb = 0; kb < K; kb += BK) {
        #pragma unroll
        for (int i = 0; i < 4; ++i) {
            gload16(gA + (size_t)i*8*K + kb, lA + i*8*BK);
            gload16(gB + (size_t)i*8*K + kb, lB + i*8*BK);
        }
        asm volatile("s_waitcnt vmcnt(0)" ::: "memory");
        __syncthreads();
        #pragma unroll
        for (int ks = 0; ks < 2; ++ks) {
            bf16x8 af[4], bfr[4];
            #pragma unroll
            for (int mt = 0; mt < 4; ++mt)
                af[mt] = *reinterpret_cast<const bf16x8*>(&As[(wy*64 + mt*16 + l16)*BK + ks*32 + quad*8]);
            #pragma unroll
            for (int nt = 0; nt < 4; ++nt)
                bfr[nt] = *reinterpret_cast<const bf16x8*>(&Bs[(wx*64 + nt*16 + l16)*BK + ks*32 + quad*8]);
            #pragma unroll
            for (int mt = 0; mt < 4; ++mt)
                #pragma unroll
                for (int nt = 0; nt < 4; ++nt)
                    acc[mt][nt] = __builtin_amdgcn_mfma_f32_16x16x32_bf16(af[mt], bfr[nt], acc[mt][nt], 0, 0, 0);
        }
        __syncthreads();
    }

    const float QSCALE = 0.180336880111f;  // 0.125 * log2(e)
    #pragma unroll
    for (int mt = 0; mt < 4; ++mt) {
        #pragma unroll
        for (int nt = 0; nt < 4; ++nt) {
            int gn = bx*BN + wx*64 + nt*16 + l16;
            float bv = bias[gn];
            #pragma unroll
            for (int r = 0; r < 4; ++r) {
                int gm = by*BM + wy*64 + mt*16 + quad*4 + r;
                float v = acc[mt][nt][r] + bv;
                if (MODE == 2) {
                    outf[(size_t)gm * N + gn] = v;
                } else if (MODE == 0) {
                    v *= QSCALE;
                    int b = gm >> 11, s = gm & 2047;
                    int h = gn >> 6,  d = gn & 63;
                    out0[(((size_t)(b*NH_ + h)*S_ + s) << 6) + d] = f2bf(v);
                } else {
                    int b = gm >> 11, s = gm & 2047;
                    if (gn < C_) {
                        int h = gn >> 6, d = gn & 63;
                        out0[(((size_t)(b*NH_ + h)*S_ + s) << 6) + d] = f2bf(v);
                    } else {
                        int n2 = gn - C_;
                        int h = n2 >> 6, d = n2 & 63;
                        out1[((size_t)(b*NH_ + h)*HD_ + d)*S_ + s] = f2bf(v);
                    }
                }
            }
        }
    }
}

// ---- fused Q-proj + KV-proj: blocks [0,512) = Q, [512,1536) = KV ----
__global__ __launch_bounds__(256)
void proj_fused(const unsigned short* __restrict__ xb, const unsigned short* __restrict__ Wqb,
                const float* __restrict__ Wq_b,
                const unsigned short* __restrict__ yb, const unsigned short* __restrict__ Wkvb,
                const float* __restrict__ Wkv_b,
                unsigned short* __restrict__ Qg, unsigned short* __restrict__ Kg,
                unsigned short* __restrict__ Vt)
{
    __shared__ unsigned short As[BM*BK];
    __shared__ unsigned short Bs[BN*BK];
    int id = blockIdx.x;
    if (id < 512) {
        gemm_body<0>(xb, Wqb, Wq_b, Qg, nullptr, nullptr, C_, C_, id & 7, id >> 3, As, Bs);
    } else {
        int j = id - 512;
        gemm_body<1>(yb, Wkvb, Wkv_b, Kg, Vt, nullptr, C_, 2*C_, j & 15, j >> 4, As, Bs);
    }
}

// ---- standalone O-projection ----
__global__ __launch_bounds__(256)
void gemm_oproj(const unsigned short* __restrict__ A, const unsigned short* __restrict__ Bt,
                const float* __restrict__ bias, float* __restrict__ outf)
{
    __shared__ unsigned short As[BM*BK];
    __shared__ unsigned short Bs[BN*BK];
    gemm_body<2>(A, Bt, bias, nullptr, nullptr, outf, C_, C_, blockIdx.x, blockIdx.y, As, Bs);
}

// ---------------- Flash attention, v3.2 (= R4's 87 µs v3.1 + micro-opts) ----------
// Wave w owns k-slice / d-slice [w*16,+16) for ALL 64 q of the tile. S^T via
// mfma(kf,qf); P packed (v_perm x2) to LDS (72-short stride = 2-way-free) with one
// ds_write_b64 per m; block-wide P exchange (2 barriers/iter); PV from Vt rows.
// Mask read per-lane as uchar4 (no precomputed bitmask kernel); zeroing of p is
// skipped wave-uniformly when all 4 bytes are 0. Diag cndmask only on diag tile.
__global__ __launch_bounds__(256, 4)
void attn_kernel(const unsigned short* __restrict__ Qg, const unsigned short* __restrict__ Kg,
                 const unsigned short* __restrict__ Vt, const unsigned char* __restrict__ maskp,
                 unsigned short* __restrict__ att)
{
    __shared__ unsigned short Pl[64*72];
    __shared__ float Lbuf[4][64];
    __shared__ float Linv[64];
    int t = threadIdx.x, lane = t & 63, w = t >> 6;
    int quad = lane >> 4, l16 = lane & 15;
    int bh = blockIdx.x, b = bh >> 4, h = bh & 15;
    int qi = blockIdx.y;

    const unsigned short* kbase = Kg + ((size_t)bh*S_ + w*16 + l16)*HD_ + quad*8;
    const unsigned short* vbase = Vt + ((size_t)bh*HD_ + w*16 + l16)*S_ + quad*8;
    int kp_row = w*16 + quad*4;   // lane's k-row base within a tile
    const unsigned char* mbase = maskp + (size_t)b*S_ + kp_row;

    for (int half = 0; half < 2; ++half) {
        int qt = half ? (NT_ - 1 - qi) : qi;

        bf16x8 qf[4][2];
        #pragma unroll
        for (int m = 0; m < 4; ++m) {
            const unsigned short* qp = Qg + ((size_t)bh*S_ + qt*64 + m*16 + l16)*HD_;
            qf[m][0] = *reinterpret_cast<const bf16x8*>(qp + quad*8);
            qf[m][1] = *reinterpret_cast<const bf16x8*>(qp + 32 + quad*8);
        }
        f32x4 oacc[4] = {};
        float lsum[4] = {0.f, 0.f, 0.f, 0.f};

        bf16x8 kc0 = *reinterpret_cast<const bf16x8*>(kbase);
        bf16x8 kc1 = *reinterpret_cast<const bf16x8*>(kbase + 32);

        for (int kt = 0; kt <= qt; ++kt) {
            int ktn = (kt < qt) ? kt + 1 : kt;
            const unsigned short* kpn = kbase + (size_t)ktn*64*HD_;
            bf16x8 kn0 = *reinterpret_cast<const bf16x8*>(kpn);
            bf16x8 kn1 = *reinterpret_cast<const bf16x8*>(kpn + 32);
            const unsigned short* vp = vbase + kt*64;
            bf16x8 vc0 = *reinterpret_cast<const bf16x8*>(vp);
            bf16x8 vc1 = *reinterpret_cast<const bf16x8*>(vp + 32);

            // lane's 4 mask bytes for kpos = kp_row..kp_row+3
            unsigned m4 = *reinterpret_cast<const unsigned*>(mbase + kt*64);

            // S^T: lane holds S^T[k = w*16+quad*4+r][q = m*16+l16]
            f32x4 sacc[4];
            #pragma unroll
            for (int m = 0; m < 4; ++m) {
                sacc[m] = __builtin_amdgcn_mfma_f32_16x16x32_bf16(kc0, qf[m][0], f32x4{}, 0, 0, 0);
                sacc[m] = __builtin_amdgcn_mfma_f32_16x16x32_bf16(kc1, qf[m][1], sacc[m], 0, 0, 0);
            }

            bool diag = (kt == qt);
            #pragma unroll
            for (int m = 0; m < 4; ++m) {
                float p[4];
                if (diag) {
                    #pragma unroll
                    for (int r = 0; r < 4; ++r) {
                        float s = sacc[m][r];
                        if (kp_row + r > m*16 + l16) s = -1e30f;
                        p[r] = __builtin_amdgcn_exp2f(s);
                    }
                } else {
                    #pragma unroll
                    for (int r = 0; r < 4; ++r)
                        p[r] = __builtin_amdgcn_exp2f(sacc[m][r]);
                }
                if (m4) {   // wave-uniform false when no padded keys in slice
                    #pragma unroll
                    for (int r = 0; r < 4; ++r)
                        if ((m4 >> (8*r)) & 0xFFu) p[r] = 0.f;
                }
                lsum[m] += (p[0] + p[1]) + (p[2] + p[3]);
                unsigned a01 = __builtin_amdgcn_perm(__float_as_uint(p[1]), __float_as_uint(p[0]), 0x07060302u);
                unsigned a23 = __builtin_amdgcn_perm(__float_as_uint(p[3]), __float_as_uint(p[2]), 0x07060302u);
                *reinterpret_cast<uint2*>(&Pl[(m*16 + l16)*72 + w*16 + quad*4]) = make_uint2(a01, a23);
            }
            __syncthreads();
            #pragma unroll
            for (int m = 0; m < 4; ++m) {
                bf16x8 pf0 = *reinterpret_cast<const bf16x8*>(&Pl[(m*16 + l16)*72 + quad*8]);
                bf16x8 pf1 = *reinterpret_cast<const bf16x8*>(&Pl[(m*16 + l16)*72 + 32 + quad*8]);
                oacc[m] = __builtin_amdgcn_mfma_f32_16x16x32_bf16(pf0, vc0, oacc[m], 0, 0, 0);
                oacc[m] = __builtin_amdgcn_mfma_f32_16x16x32_bf16(pf1, vc1, oacc[m], 0, 0, 0);
            }
            __syncthreads();
            kc0 = kn0; kc1 = kn1;
        }

        // ---- epilogue: quad-reduce lsum, cross-wave L, store O/l ----
        #pragma unroll
        for (int m = 0; m < 4; ++m) {
            lsum[m] += __shfl_xor(lsum[m], 16, 64);
            lsum[m] += __shfl_xor(lsum[m], 32, 64);
            Lbuf[w][m*16 + l16] = lsum[m];
        }
        __syncthreads();
        int q64 = t & 63;
        Linv[q64] = 1.0f / (Lbuf[0][q64] + Lbuf[1][q64] + Lbuf[2][q64] + Lbuf[3][q64]);
        __syncthreads();
        #pragma unroll
        for (int m = 0; m < 4; ++m) {
            #pragma unroll
            for (int r = 0; r < 4; ++r) {
                float iv = Linv[m*16 + quad*4 + r];
                int q = qt*64 + m*16 + quad*4 + r;
                att[((size_t)(b*S_ + q))*C_ + h*HD_ + w*16 + l16] = f2bf(oacc[m][r] * iv);
            }
        }
        __syncthreads();   // Pl/Linv reuse barrier before next half
    }
}

// ---------------- launch ----------------
extern "C" void kernel_launch(void* const* d_in, const int* in_sizes, int n_in,
                              void* d_out, int out_size, void* d_ws, size_t ws_size,
                              hipStream_t stream) {
    const float* x     = (const float*)d_in[0];
    const float* y     = (const float*)d_in[1];
    const unsigned char* mask = (const unsigned char*)d_in[2];
    const float* Wq_w  = (const float*)d_in[3];
    const float* Wq_b  = (const float*)d_in[4];
    const float* Wkv_w = (const float*)d_in[5];
    const float* Wkv_b = (const float*)d_in[6];
    const float* Wo_w  = (const float*)d_in[7];
    const float* Wo_b  = (const float*)d_in[8];
    float* out = (float*)d_out;

    unsigned short* xb   = (unsigned short*)d_ws;
    unsigned short* yb   = xb   + (size_t)M_*C_;
    unsigned short* Wqb  = yb   + (size_t)M_*C_;
    unsigned short* Wkvb = Wqb  + (size_t)C_*C_;
    unsigned short* Wob  = Wkvb + (size_t)2*C_*C_;
    unsigned short* Qg   = Wob  + (size_t)C_*C_;
    unsigned short* Kg   = Qg   + (size_t)M_*C_;
    unsigned short* Vtg  = Kg   + (size_t)M_*C_;
    unsigned short* att  = xb;   // xb dead after Q proj

    cvt_all<<<10240, 256, 0, stream>>>((const float4*)x, (const float4*)y,
        (const float4*)Wq_w, (const float4*)Wkv_w, (const float4*)Wo_w,
        (uint4*)xb, (uint4*)yb, (uint4*)Wqb, (uint4*)Wkvb, (uint4*)Wob);

    proj_fused<<<1536, 256, 0, stream>>>(xb, Wqb, Wq_b, yb, Wkvb, Wkv_b, Qg, Kg, Vtg);
    attn_kernel<<<dim3(B_*NH_, NT_/2), 256, 0, stream>>>(Qg, Kg, Vtg, mask, att);
    gemm_oproj<<<dim3(C_/BN, M_/BM), 256, 0, stream>>>(att, Wob, Wo_b, out);
}